// Round 10
// baseline (972.250 us; speedup 1.0000x reference)
//
#include <hip/hip_runtime.h>
#include <hip/hip_fp16.h>

// GCN 2-layer forward, MI355X. R10: revert R9's reorder regressions + fold
// degree counting into reorder on the TCC atomic pipe.
// R9 post-mortem: NT stores broke L2 write-merging (WRITE 88->107MB) and u64
// staging didn't cut conflicts (placement+hist atomics dominate) => reorder
// back to R8 form (b32 sorted + u16 sbb, plain loads/stores).
// New: reorder phase 1 also does global atomicAdd(&deg[dst],1) — dst is
// already in a register; global atomics run in the L2/TCC atomic units, a
// DIFFERENT pipe from the LDS-atomic governor => mostly overlapped. The
// per-edge dinv pass is deleted; k_node (node-parallel, ~8us) computes
// dinv/xs from deg.
// Kept: W=2048 multisplit, 1x u64 fixed-point LDS atomic/edge in acc with
// x2-replicated accumulators + 8-deep gather unroll, fused MLP flush.
// Pipeline: memset(fill,deg), reorder(+deg), node, acc1(+full MLP), acc2.

constexpr int W_SHIFT = 11;
constexpr int W = 2048;            // nodes per dst window
constexpr int MAXB = 512;          // max buckets
constexpr int RB = 1024;           // reorder block threads
constexpr int CHUNK = 8192;        // edges per reorder block
constexpr int AB = 512;            // accumulate block threads

constexpr float SCALE1 = 65536.0f;        // 2^16
constexpr float INV1   = 1.0f / 65536.0f;
constexpr unsigned BIAS1 = 1u << 20;
constexpr float SCALE2 = 4096.0f;         // 2^12
constexpr float INV2   = 1.0f / 4096.0f;
constexpr unsigned BIAS2 = 1u << 22;

typedef unsigned uv4 __attribute__((ext_vector_type(4)));
typedef int      iv4 __attribute__((ext_vector_type(4)));

__device__ __forceinline__ unsigned long long pack2(float a, float b,
                                                    float scale, unsigned bias) {
    unsigned lo = (unsigned)(__float2int_rn(a * scale) + (int)bias);
    unsigned hi = (unsigned)(__float2int_rn(b * scale) + (int)bias);
    return (unsigned long long)lo | ((unsigned long long)hi << 32);
}

// LDS multisplit + global degree count (TCC atomic pipe).
// fill[b] counts edges per window (memset-0); slab base = b*C.
__global__ __launch_bounds__(RB) void k_reorder(const int* __restrict__ src,
                                                const int* __restrict__ dst,
                                                unsigned* __restrict__ fill,
                                                unsigned* __restrict__ perm,
                                                unsigned* __restrict__ deg,
                                                int E, unsigned C) {
    __shared__ unsigned hist[MAXB];       // counts -> running local ptr
    __shared__ unsigned lbase[MAXB];      // scan scratch
    __shared__ unsigned gdelta[MAXB];     // globalPos - localPos
    __shared__ unsigned sorted[CHUNK];    // vals in locally-sorted order
    __shared__ unsigned short sbb[CHUNK]; // bucket of sorted[t]
    int tid = threadIdx.x;
    if (tid < MAXB) hist[tid] = 0u;
    __syncthreads();
    long base0 = (long)blockIdx.x * CHUNK;
    int total = (int)min((long)CHUNK, (long)E - base0);
    bool full = (total == CHUNK);

    if (full) {
        const iv4* dv4 = (const iv4*)(dst + base0);
        #pragma unroll
        for (int k = 0; k < 2; k++) {
            iv4 q = dv4[k * RB + tid];
            atomicAdd(&hist[((unsigned)q.x) >> W_SHIFT], 1u);
            atomicAdd(&hist[((unsigned)q.y) >> W_SHIFT], 1u);
            atomicAdd(&hist[((unsigned)q.z) >> W_SHIFT], 1u);
            atomicAdd(&hist[((unsigned)q.w) >> W_SHIFT], 1u);
            atomicAdd(&deg[(unsigned)q.x], 1u);   // TCC pipe, overlaps LDS
            atomicAdd(&deg[(unsigned)q.y], 1u);
            atomicAdd(&deg[(unsigned)q.z], 1u);
            atomicAdd(&deg[(unsigned)q.w], 1u);
        }
    } else {
        for (int li = tid; li < total; li += RB) {
            unsigned d = (unsigned)dst[base0 + li];
            atomicAdd(&hist[d >> W_SHIFT], 1u);
            atomicAdd(&deg[d], 1u);
        }
    }
    __syncthreads();
    // inclusive Hillis-Steele scan over MAXB buckets
    unsigned v = (tid < MAXB) ? hist[tid] : 0u;
    if (tid < MAXB) lbase[tid] = v;
    __syncthreads();
    for (int off = 1; off < MAXB; off <<= 1) {
        unsigned u = (tid >= off && tid < MAXB) ? lbase[tid - off] : 0u;
        __syncthreads();
        if (tid < MAXB) lbase[tid] += u;
        __syncthreads();
    }
    if (tid < MAXB) {
        unsigned excl = lbase[tid] - v;
        unsigned gd = 0u;
        if (v) gd = (unsigned)tid * C + atomicAdd(&fill[tid], v) - excl;
        gdelta[tid] = gd;
        hist[tid] = excl;   // running local write ptr
    }
    __syncthreads();
    if (full) {
        const iv4* dv4 = (const iv4*)(dst + base0);
        const iv4* sv4 = (const iv4*)(src + base0);
        #pragma unroll
        for (int k = 0; k < 2; k++) {
            iv4 dq = dv4[k * RB + tid];
            iv4 sq = sv4[k * RB + tid];
            unsigned d, b, lpos;
            d = (unsigned)dq.x; b = d >> W_SHIFT; lpos = atomicAdd(&hist[b], 1u);
            sorted[lpos] = (unsigned)sq.x | ((d & (W - 1)) << 20); sbb[lpos] = (unsigned short)b;
            d = (unsigned)dq.y; b = d >> W_SHIFT; lpos = atomicAdd(&hist[b], 1u);
            sorted[lpos] = (unsigned)sq.y | ((d & (W - 1)) << 20); sbb[lpos] = (unsigned short)b;
            d = (unsigned)dq.z; b = d >> W_SHIFT; lpos = atomicAdd(&hist[b], 1u);
            sorted[lpos] = (unsigned)sq.z | ((d & (W - 1)) << 20); sbb[lpos] = (unsigned short)b;
            d = (unsigned)dq.w; b = d >> W_SHIFT; lpos = atomicAdd(&hist[b], 1u);
            sorted[lpos] = (unsigned)sq.w | ((d & (W - 1)) << 20); sbb[lpos] = (unsigned short)b;
        }
    } else {
        for (int li = tid; li < total; li += RB) {
            unsigned d = (unsigned)dst[base0 + li];
            unsigned s = (unsigned)src[base0 + li];
            unsigned b = d >> W_SHIFT;
            unsigned lpos = atomicAdd(&hist[b], 1u);
            sorted[lpos] = s | ((d & (W - 1)) << 20);
            sbb[lpos] = (unsigned short)b;
        }
    }
    __syncthreads();
    if (full) {
        #pragma unroll
        for (int k = 0; k < CHUNK / RB; k++) {
            int t = k * RB + tid;
            unsigned b = sbb[t];
            perm[gdelta[b] + t] = sorted[t];   // piecewise-contiguous targets
        }
    } else {
        for (int t = tid; t < total; t += RB) {
            unsigned b = sbb[t];
            perm[gdelta[b] + t] = sorted[t];
        }
    }
}

// node-parallel: dinv = 1/sqrt(deg+1); xs = half2(x*dinv). No edge pass.
__global__ __launch_bounds__(256) void k_node(const unsigned* __restrict__ deg,
                                              const float2* __restrict__ x,
                                              float* __restrict__ dinv,
                                              __half2* __restrict__ xs, int n) {
    int i = blockIdx.x * 256 + threadIdx.x;
    if (i >= n) return;
    float dv = 1.0f / sqrtf((float)(deg[i] + 1u));  // +1 self-loop
    dinv[i] = dv;
    float2 xv = x[i];
    xs[i] = __floats2half2_rn(xv.x * dv, xv.y * dv);
}

// layer1 aggregate (1 u64 fixed-point atomic/edge, x2-replicated acc) + MLP
__global__ __launch_bounds__(AB) void k_acc1(const unsigned* __restrict__ perm,
                                             const unsigned* __restrict__ fill,
                                             const __half2* __restrict__ xs,
                                             const float* __restrict__ dinv,
                                             const unsigned* __restrict__ deg,
                                             const float* __restrict__ W1,
                                             const float* __restrict__ b1,
                                             const float* __restrict__ W2,
                                             __half2* __restrict__ h2s,
                                             int N, unsigned C) {
    __shared__ unsigned long long acc[2 * W];
    for (int i = threadIdx.x; i < 2 * W; i += AB) acc[i] = 0ull;
    __syncthreads();
    int b = blockIdx.x;
    unsigned par = threadIdx.x & 1u;
    unsigned s = (unsigned)b * C, e = s + fill[b];
    unsigned m = e - s, nv8 = m >> 3;
    const uv4* p4 = (const uv4*)(perm + s);
    for (unsigned j = threadIdx.x; j < nv8; j += AB) {
        uv4 qa = __builtin_nontemporal_load(p4 + 2u * j);
        uv4 qb = __builtin_nontemporal_load(p4 + 2u * j + 1u);
        float2 v0 = __half22float2(xs[qa.x & 0xFFFFFu]);
        float2 v1 = __half22float2(xs[qa.y & 0xFFFFFu]);
        float2 v2 = __half22float2(xs[qa.z & 0xFFFFFu]);
        float2 v3 = __half22float2(xs[qa.w & 0xFFFFFu]);
        float2 v4 = __half22float2(xs[qb.x & 0xFFFFFu]);
        float2 v5 = __half22float2(xs[qb.y & 0xFFFFFu]);
        float2 v6 = __half22float2(xs[qb.z & 0xFFFFFu]);
        float2 v7 = __half22float2(xs[qb.w & 0xFFFFFu]);
        atomicAdd(&acc[((qa.x >> 20) << 1) | par], pack2(v0.x, v0.y, SCALE1, BIAS1));
        atomicAdd(&acc[((qa.y >> 20) << 1) | par], pack2(v1.x, v1.y, SCALE1, BIAS1));
        atomicAdd(&acc[((qa.z >> 20) << 1) | par], pack2(v2.x, v2.y, SCALE1, BIAS1));
        atomicAdd(&acc[((qa.w >> 20) << 1) | par], pack2(v3.x, v3.y, SCALE1, BIAS1));
        atomicAdd(&acc[((qb.x >> 20) << 1) | par], pack2(v4.x, v4.y, SCALE1, BIAS1));
        atomicAdd(&acc[((qb.y >> 20) << 1) | par], pack2(v5.x, v5.y, SCALE1, BIAS1));
        atomicAdd(&acc[((qb.z >> 20) << 1) | par], pack2(v6.x, v6.y, SCALE1, BIAS1));
        atomicAdd(&acc[((qb.w >> 20) << 1) | par], pack2(v7.x, v7.y, SCALE1, BIAS1));
    }
    unsigned t = s + (nv8 << 3) + threadIdx.x;
    if (t < e) {
        unsigned p = perm[t];
        float2 v = __half22float2(xs[p & 0xFFFFFu]);
        atomicAdd(&acc[((p >> 20) << 1) | par], pack2(v.x, v.y, SCALE1, BIAS1));
    }
    __syncthreads();
    int d0 = b << W_SHIFT;
    float w10 = W1[0], w11 = W1[1], w12 = W1[2], w13 = W1[3];
    float w14 = W1[4], w15 = W1[5], w16 = W1[6], w17 = W1[7];
    float bb0 = b1[0], bb1 = b1[1], bb2 = b1[2], bb3 = b1[3];
    float u0 = W2[0], u1 = W2[1], u2 = W2[2], u3 = W2[3];
    float u4 = W2[4], u5 = W2[5], u6 = W2[6], u7 = W2[7];
    for (int l = threadIdx.x; l < W; l += AB) {
        int d = d0 + l;
        if (d < N) {
            float dv = dinv[d];
            unsigned cn = deg[d];
            unsigned long long a64 = acc[2 * l] + acc[2 * l + 1];
            unsigned lo = (unsigned)a64, hi = (unsigned)(a64 >> 32);
            float2 self = __half22float2(xs[d]);
            float Sx = (float)(int)(lo - cn * BIAS1) * INV1 + self.x;
            float Sy = (float)(int)(hi - cn * BIAS1) * INV1 + self.y;
            float a0 = fmaxf(fmaf(Sy, w14, Sx * w10) * dv + bb0, 0.0f);
            float a1 = fmaxf(fmaf(Sy, w15, Sx * w11) * dv + bb1, 0.0f);
            float a2 = fmaxf(fmaf(Sy, w16, Sx * w12) * dv + bb2, 0.0f);
            float a3 = fmaxf(fmaf(Sy, w17, Sx * w13) * dv + bb3, 0.0f);
            float hx = (a0 * u0 + a1 * u2 + a2 * u4 + a3 * u6) * dv;
            float hy = (a0 * u1 + a1 * u3 + a2 * u5 + a3 * u7) * dv;
            h2s[d] = __floats2half2_rn(hx, hy);
        }
    }
}

__global__ __launch_bounds__(AB) void k_acc2(const unsigned* __restrict__ perm,
                                             const unsigned* __restrict__ fill,
                                             const __half2* __restrict__ h2s,
                                             const float* __restrict__ dinv,
                                             const unsigned* __restrict__ deg,
                                             const float* __restrict__ b2,
                                             float2* __restrict__ out,
                                             int N, unsigned C) {
    __shared__ unsigned long long acc[2 * W];
    for (int i = threadIdx.x; i < 2 * W; i += AB) acc[i] = 0ull;
    __syncthreads();
    int b = blockIdx.x;
    unsigned par = threadIdx.x & 1u;
    unsigned s = (unsigned)b * C, e = s + fill[b];
    unsigned m = e - s, nv8 = m >> 3;
    const uv4* p4 = (const uv4*)(perm + s);
    for (unsigned j = threadIdx.x; j < nv8; j += AB) {
        uv4 qa = __builtin_nontemporal_load(p4 + 2u * j);
        uv4 qb = __builtin_nontemporal_load(p4 + 2u * j + 1u);
        float2 v0 = __half22float2(h2s[qa.x & 0xFFFFFu]);
        float2 v1 = __half22float2(h2s[qa.y & 0xFFFFFu]);
        float2 v2 = __half22float2(h2s[qa.z & 0xFFFFFu]);
        float2 v3 = __half22float2(h2s[qa.w & 0xFFFFFu]);
        float2 v4 = __half22float2(h2s[qb.x & 0xFFFFFu]);
        float2 v5 = __half22float2(h2s[qb.y & 0xFFFFFu]);
        float2 v6 = __half22float2(h2s[qb.z & 0xFFFFFu]);
        float2 v7 = __half22float2(h2s[qb.w & 0xFFFFFu]);
        atomicAdd(&acc[((qa.x >> 20) << 1) | par], pack2(v0.x, v0.y, SCALE2, BIAS2));
        atomicAdd(&acc[((qa.y >> 20) << 1) | par], pack2(v1.x, v1.y, SCALE2, BIAS2));
        atomicAdd(&acc[((qa.z >> 20) << 1) | par], pack2(v2.x, v2.y, SCALE2, BIAS2));
        atomicAdd(&acc[((qa.w >> 20) << 1) | par], pack2(v3.x, v3.y, SCALE2, BIAS2));
        atomicAdd(&acc[((qb.x >> 20) << 1) | par], pack2(v4.x, v4.y, SCALE2, BIAS2));
        atomicAdd(&acc[((qb.y >> 20) << 1) | par], pack2(v5.x, v5.y, SCALE2, BIAS2));
        atomicAdd(&acc[((qb.z >> 20) << 1) | par], pack2(v6.x, v6.y, SCALE2, BIAS2));
        atomicAdd(&acc[((qb.w >> 20) << 1) | par], pack2(v7.x, v7.y, SCALE2, BIAS2));
    }
    unsigned t = s + (nv8 << 3) + threadIdx.x;
    if (t < e) {
        unsigned p = perm[t];
        float2 v = __half22float2(h2s[p & 0xFFFFFu]);
        atomicAdd(&acc[((p >> 20) << 1) | par], pack2(v.x, v.y, SCALE2, BIAS2));
    }
    __syncthreads();
    int d0 = b << W_SHIFT;
    float bb0 = b2[0], bb1 = b2[1];
    for (int l = threadIdx.x; l < W; l += AB) {
        int d = d0 + l;
        if (d < N) {
            float dv = dinv[d];
            unsigned cn = deg[d];
            unsigned long long a64 = acc[2 * l] + acc[2 * l + 1];
            unsigned lo = (unsigned)a64, hi = (unsigned)(a64 >> 32);
            float2 v = __half22float2(h2s[d]);
            float Sx = (float)(int)(lo - cn * BIAS2) * INV2 + v.x;
            float Sy = (float)(int)(hi - cn * BIAS2) * INV2 + v.y;
            out[d] = make_float2(Sx * dv + bb0, Sy * dv + bb1);
        }
    }
}

// ---------------- fallback (R1-style, only if workspace too small) ----------

__global__ __launch_bounds__(256) void f_init_deg(unsigned* deg, int n) {
    int i = blockIdx.x * 256 + threadIdx.x;
    if (i < n) deg[i] = 1u;
}
__global__ __launch_bounds__(256) void f_count_deg(const int* dst, unsigned* deg, int E) {
    int e = blockIdx.x * 256 + threadIdx.x;
    if (e < E) atomicAdd(&deg[dst[e]], 1u);
}
__global__ __launch_bounds__(256) void f_node1(const float2* x, const float* W1,
                                               const unsigned* deg, float* dinv,
                                               float4* h1s, float4* agg1, int n) {
    int i = blockIdx.x * 256 + threadIdx.x;
    if (i >= n) return;
    float dv = 1.0f / sqrtf((float)deg[i]);
    dinv[i] = dv;
    float2 xv = x[i];
    float4 h;
    h.x = fmaf(xv.y, W1[4], xv.x * W1[0]) * dv;
    h.y = fmaf(xv.y, W1[5], xv.x * W1[1]) * dv;
    h.z = fmaf(xv.y, W1[6], xv.x * W1[2]) * dv;
    h.w = fmaf(xv.y, W1[7], xv.x * W1[3]) * dv;
    h1s[i] = h;
    agg1[i] = make_float4(h.x * dv, h.y * dv, h.z * dv, h.w * dv);
}
__global__ __launch_bounds__(256) void f_edge1(const int* src, const int* dst,
                                               const float* dinv, const float4* h1s,
                                               float* agg1, int E) {
    int e = blockIdx.x * 256 + threadIdx.x;
    if (e >= E) return;
    int s = src[e], d = dst[e];
    float w = dinv[d];
    float4 m = h1s[s];
    float* p = agg1 + 4ll * d;
    unsafeAtomicAdd(p + 0, m.x * w);
    unsafeAtomicAdd(p + 1, m.y * w);
    unsafeAtomicAdd(p + 2, m.z * w);
    unsafeAtomicAdd(p + 3, m.w * w);
}
__global__ __launch_bounds__(256) void f_node2(const float4* agg1, const float* b1,
                                               const float* W2, const float* b2,
                                               const float* dinv, float2* h2s,
                                               float2* out, int n) {
    int i = blockIdx.x * 256 + threadIdx.x;
    if (i >= n) return;
    float4 a = agg1[i];
    a.x = fmaxf(a.x + b1[0], 0.0f);
    a.y = fmaxf(a.y + b1[1], 0.0f);
    a.z = fmaxf(a.z + b1[2], 0.0f);
    a.w = fmaxf(a.w + b1[3], 0.0f);
    float dv = dinv[i];
    float2 h;
    h.x = (a.x * W2[0] + a.y * W2[2] + a.z * W2[4] + a.w * W2[6]) * dv;
    h.y = (a.x * W2[1] + a.y * W2[3] + a.z * W2[5] + a.w * W2[7]) * dv;
    h2s[i] = h;
    out[i] = make_float2(b2[0] + h.x * dv, b2[1] + h.y * dv);
}
__global__ __launch_bounds__(256) void f_edge2(const int* src, const int* dst,
                                               const float* dinv, const float2* h2s,
                                               float* out, int E) {
    int e = blockIdx.x * 256 + threadIdx.x;
    if (e >= E) return;
    int s = src[e], d = dst[e];
    float w = dinv[d];
    float2 m = h2s[s];
    float* p = out + 2ll * d;
    unsafeAtomicAdd(p + 0, m.x * w);
    unsafeAtomicAdd(p + 1, m.y * w);
}

extern "C" void kernel_launch(void* const* d_in, const int* in_sizes, int n_in,
                              void* d_out, int out_size, void* d_ws, size_t ws_size,
                              hipStream_t stream) {
    const float* x  = (const float*)d_in[0];
    const int* ei   = (const int*)d_in[1];
    const float* W1 = (const float*)d_in[2];
    const float* b1 = (const float*)d_in[3];
    const float* W2 = (const float*)d_in[4];
    const float* b2 = (const float*)d_in[5];
    float* out = (float*)d_out;

    const int N = in_sizes[0] / 2;
    const int E = in_sizes[1] / 2;
    const int* src = ei;
    const int* dst = ei + E;
    const int NB = (N + W - 1) >> W_SHIFT;

    char* ws = (char*)d_ws;
    const int gN = (N + 255) / 256;
    const int gE = (E + 255) / 256;

    // slab capacity: mean fill E/NB (~32.7K, sigma~181); margin 4096 (>20σ)
    size_t fixed = 32768 + (size_t)16 * N;   // fill | dinv | deg | xs | h2s
    long avail = (long)ws_size - (long)fixed;
    long Cmax = (avail > 0) ? avail / (4L * NB) : 0;
    long Cmin = (long)(E / (NB > 0 ? NB : 1)) + 4096;
    long Cw = (Cmax > Cmin + 8192) ? (Cmin + 8192) : Cmax;
    unsigned C = (unsigned)(Cw & ~7L);       // multiple of 8 for uint4x2 loads
    bool fast = ((long)C >= Cmin) && (NB <= MAXB) && (N <= (1 << 20));

    if (fast) {
        unsigned* fill = (unsigned*)(ws);                          // NB counts
        float*    dinv = (float*)(ws + 32768);
        unsigned* deg  = (unsigned*)(ws + 32768 + (size_t)4 * N);
        __half2*  xs   = (__half2*)(ws + 32768 + (size_t)8 * N);
        __half2*  h2s  = (__half2*)(ws + 32768 + (size_t)12 * N);
        unsigned* perm = (unsigned*)(ws + fixed);

        hipMemsetAsync(fill, 0, (size_t)NB * 4, stream);
        hipMemsetAsync(deg, 0, (size_t)N * 4, stream);
        k_reorder<<<(E + CHUNK - 1) / CHUNK, RB, 0, stream>>>(src, dst, fill, perm,
                                                              deg, E, C);
        k_node<<<gN, 256, 0, stream>>>(deg, (const float2*)x, dinv, xs, N);
        k_acc1<<<NB, AB, 0, stream>>>(perm, fill, xs, dinv, deg, W1, b1, W2, h2s, N, C);
        k_acc2<<<NB, AB, 0, stream>>>(perm, fill, h2s, dinv, deg, b2, (float2*)out, N, C);
    } else {
        unsigned* deg = (unsigned*)(ws);
        float* dinv   = (float*)(ws + (size_t)4 * N);
        float* h1s    = (float*)(ws + (size_t)8 * N);
        float* agg1   = (float*)(ws + (size_t)24 * N);
        float* h2s    = h1s;

        f_init_deg<<<gN, 256, 0, stream>>>(deg, N);
        f_count_deg<<<gE, 256, 0, stream>>>(dst, deg, E);
        f_node1<<<gN, 256, 0, stream>>>((const float2*)x, W1, deg, dinv,
                                        (float4*)h1s, (float4*)agg1, N);
        f_edge1<<<gE, 256, 0, stream>>>(src, dst, dinv, (const float4*)h1s, agg1, E);
        f_node2<<<gN, 256, 0, stream>>>((const float4*)agg1, b1, W2, b2, dinv,
                                        (float2*)h2s, (float2*)out, N);
        f_edge2<<<gE, 256, 0, stream>>>(src, dst, dinv, (const float2*)h2s, out, E);
    }
}

// Round 11
// 433.344 us; speedup vs baseline: 2.2436x; 2.2436x over previous
//
#include <hip/hip_runtime.h>
#include <hip/hip_fp16.h>

// GCN 2-layer forward, MI355X. R11: revert to the measured-optimal R8 config.
// R10 post-mortem: 16M random global atomicAdd(&deg,1) in reorder => 583MB
// write-back (64B line dirtied per atomic), serialized phase 1 (645us).
// Confirmed twice (R1, R10): random global atomics are ~6x the cost of an
// LDS-atomic pass — never trade LDS atomics for them.
// Structural model (R5-R8): five per-edge LDS-atomic ops across 4 passes
// (reorder hist+placement, dinv count, acc1, acc2), each at its ~3.5cyc/edge
// fixed-function floor, invariant to width/banking/occupancy. All remaining
// atomic instructions are algorithmically required. This config = 435us.
// Pipeline: zero_fill, reorder, dinv(+deg+xs), acc1(+full MLP), acc2.

constexpr int W_SHIFT = 11;
constexpr int W = 2048;            // nodes per dst window
constexpr int MAXB = 512;          // max buckets
constexpr int RB = 1024;           // reorder block threads
constexpr int CHUNK = 8192;        // edges per reorder block
constexpr int AB = 512;            // accumulate block threads

constexpr float SCALE1 = 65536.0f;        // 2^16
constexpr float INV1   = 1.0f / 65536.0f;
constexpr unsigned BIAS1 = 1u << 20;
constexpr float SCALE2 = 4096.0f;         // 2^12
constexpr float INV2   = 1.0f / 4096.0f;
constexpr unsigned BIAS2 = 1u << 22;

typedef unsigned uv4 __attribute__((ext_vector_type(4)));
typedef int      iv4 __attribute__((ext_vector_type(4)));

__device__ __forceinline__ unsigned long long pack2(float a, float b,
                                                    float scale, unsigned bias) {
    unsigned lo = (unsigned)(__float2int_rn(a * scale) + (int)bias);
    unsigned hi = (unsigned)(__float2int_rn(b * scale) + (int)bias);
    return (unsigned long long)lo | ((unsigned long long)hi << 32);
}

__global__ __launch_bounds__(256) void k_zero_fill(unsigned* __restrict__ fill,
                                                   int nb, unsigned C) {
    int i = blockIdx.x * 256 + threadIdx.x;
    if (i < nb) fill[i] = (unsigned)i * C;
}

// LDS multisplit: bin CHUNK edges into dst windows with coalesced output.
__global__ __launch_bounds__(RB) void k_reorder(const int* __restrict__ src,
                                                const int* __restrict__ dst,
                                                unsigned* __restrict__ fill,
                                                unsigned* __restrict__ perm, int E) {
    __shared__ unsigned hist[MAXB];       // counts -> running local ptr
    __shared__ unsigned lbase[MAXB];      // scan scratch -> inclusive scan
    __shared__ unsigned gdelta[MAXB];     // globalBase - localBase
    __shared__ unsigned sorted[CHUNK];    // vals in locally-sorted order
    __shared__ unsigned short sbb[CHUNK]; // bucket of sorted[t]
    int tid = threadIdx.x;
    if (tid < MAXB) hist[tid] = 0u;
    __syncthreads();
    long base0 = (long)blockIdx.x * CHUNK;
    int total = (int)min((long)CHUNK, (long)E - base0);
    bool full = (total == CHUNK);

    if (full) {
        const iv4* dv4 = (const iv4*)(dst + base0);
        #pragma unroll
        for (int k = 0; k < 2; k++) {
            iv4 q = dv4[k * RB + tid];
            atomicAdd(&hist[((unsigned)q.x) >> W_SHIFT], 1u);
            atomicAdd(&hist[((unsigned)q.y) >> W_SHIFT], 1u);
            atomicAdd(&hist[((unsigned)q.z) >> W_SHIFT], 1u);
            atomicAdd(&hist[((unsigned)q.w) >> W_SHIFT], 1u);
        }
    } else {
        for (int li = tid; li < total; li += RB)
            atomicAdd(&hist[((unsigned)dst[base0 + li]) >> W_SHIFT], 1u);
    }
    __syncthreads();
    // inclusive Hillis-Steele scan over MAXB buckets
    unsigned v = (tid < MAXB) ? hist[tid] : 0u;
    if (tid < MAXB) lbase[tid] = v;
    __syncthreads();
    for (int off = 1; off < MAXB; off <<= 1) {
        unsigned u = (tid >= off && tid < MAXB) ? lbase[tid - off] : 0u;
        __syncthreads();
        if (tid < MAXB) lbase[tid] += u;
        __syncthreads();
    }
    if (tid < MAXB) {
        unsigned excl = lbase[tid] - v;
        unsigned gd = 0u;
        if (v) gd = atomicAdd(&fill[tid], v) - excl;  // reserve slab space
        gdelta[tid] = gd;
        hist[tid] = excl;   // running local write ptr
    }
    __syncthreads();
    if (full) {
        const iv4* dv4 = (const iv4*)(dst + base0);
        const iv4* sv4 = (const iv4*)(src + base0);
        #pragma unroll
        for (int k = 0; k < 2; k++) {
            iv4 dq = dv4[k * RB + tid];
            iv4 sq = sv4[k * RB + tid];
            unsigned d, b, lpos;
            d = (unsigned)dq.x; b = d >> W_SHIFT; lpos = atomicAdd(&hist[b], 1u);
            sorted[lpos] = (unsigned)sq.x | ((d & (W - 1)) << 20); sbb[lpos] = (unsigned short)b;
            d = (unsigned)dq.y; b = d >> W_SHIFT; lpos = atomicAdd(&hist[b], 1u);
            sorted[lpos] = (unsigned)sq.y | ((d & (W - 1)) << 20); sbb[lpos] = (unsigned short)b;
            d = (unsigned)dq.z; b = d >> W_SHIFT; lpos = atomicAdd(&hist[b], 1u);
            sorted[lpos] = (unsigned)sq.z | ((d & (W - 1)) << 20); sbb[lpos] = (unsigned short)b;
            d = (unsigned)dq.w; b = d >> W_SHIFT; lpos = atomicAdd(&hist[b], 1u);
            sorted[lpos] = (unsigned)sq.w | ((d & (W - 1)) << 20); sbb[lpos] = (unsigned short)b;
        }
    } else {
        for (int li = tid; li < total; li += RB) {
            unsigned d = (unsigned)dst[base0 + li];
            unsigned s = (unsigned)src[base0 + li];
            unsigned b = d >> W_SHIFT;
            unsigned lpos = atomicAdd(&hist[b], 1u);
            sorted[lpos] = s | ((d & (W - 1)) << 20);
            sbb[lpos] = (unsigned short)b;
        }
    }
    __syncthreads();
    if (full) {
        #pragma unroll
        for (int k = 0; k < CHUNK / RB; k++) {
            int t = k * RB + tid;
            unsigned b = sbb[t];
            perm[gdelta[b] + t] = sorted[t];   // piecewise-contiguous targets
        }
    } else {
        for (int t = tid; t < total; t += RB) {
            unsigned b = sbb[t];
            perm[gdelta[b] + t] = sorted[t];
        }
    }
}

// degree count (x2-replicated LDS histogram) + dinv + deg + xs, fused
__global__ __launch_bounds__(AB) void k_dinv(const unsigned* __restrict__ perm,
                                             const unsigned* __restrict__ fill,
                                             const float2* __restrict__ x,
                                             float* __restrict__ dinv,
                                             unsigned* __restrict__ deg,
                                             __half2* __restrict__ xs,
                                             int N, unsigned C) {
    __shared__ unsigned c[2 * W];
    for (int i = threadIdx.x; i < 2 * W; i += AB) c[i] = 0u;
    __syncthreads();
    int b = blockIdx.x;
    unsigned par = threadIdx.x & 1u;
    unsigned s = (unsigned)b * C, e = fill[b];
    unsigned m = e - s, nv8 = m >> 3;
    const uv4* p4 = (const uv4*)(perm + s);
    for (unsigned j = threadIdx.x; j < nv8; j += AB) {
        uv4 qa = __builtin_nontemporal_load(p4 + 2u * j);
        uv4 qb = __builtin_nontemporal_load(p4 + 2u * j + 1u);
        atomicAdd(&c[((qa.x >> 20) << 1) | par], 1u);
        atomicAdd(&c[((qa.y >> 20) << 1) | par], 1u);
        atomicAdd(&c[((qa.z >> 20) << 1) | par], 1u);
        atomicAdd(&c[((qa.w >> 20) << 1) | par], 1u);
        atomicAdd(&c[((qb.x >> 20) << 1) | par], 1u);
        atomicAdd(&c[((qb.y >> 20) << 1) | par], 1u);
        atomicAdd(&c[((qb.z >> 20) << 1) | par], 1u);
        atomicAdd(&c[((qb.w >> 20) << 1) | par], 1u);
    }
    unsigned t = s + (nv8 << 3) + threadIdx.x;
    if (t < e) atomicAdd(&c[((perm[t] >> 20) << 1) | par], 1u);
    __syncthreads();
    int d0 = b << W_SHIFT;
    for (int l = threadIdx.x; l < W; l += AB) {
        int d = d0 + l;
        if (d < N) {
            unsigned cn = c[2 * l] + c[2 * l + 1];
            float dv = 1.0f / sqrtf((float)(cn + 1u));  // +1 self-loop
            dinv[d] = dv;
            deg[d] = cn;
            float2 xv = x[d];
            xs[d] = __floats2half2_rn(xv.x * dv, xv.y * dv);
        }
    }
}

// layer1 aggregate (1 u64 fixed-point atomic/edge, x2-replicated acc) + MLP
__global__ __launch_bounds__(AB) void k_acc1(const unsigned* __restrict__ perm,
                                             const unsigned* __restrict__ fill,
                                             const __half2* __restrict__ xs,
                                             const float* __restrict__ dinv,
                                             const unsigned* __restrict__ deg,
                                             const float* __restrict__ W1,
                                             const float* __restrict__ b1,
                                             const float* __restrict__ W2,
                                             __half2* __restrict__ h2s,
                                             int N, unsigned C) {
    __shared__ unsigned long long acc[2 * W];
    for (int i = threadIdx.x; i < 2 * W; i += AB) acc[i] = 0ull;
    __syncthreads();
    int b = blockIdx.x;
    unsigned par = threadIdx.x & 1u;
    unsigned s = (unsigned)b * C, e = fill[b];
    unsigned m = e - s, nv8 = m >> 3;
    const uv4* p4 = (const uv4*)(perm + s);
    for (unsigned j = threadIdx.x; j < nv8; j += AB) {
        uv4 qa = __builtin_nontemporal_load(p4 + 2u * j);
        uv4 qb = __builtin_nontemporal_load(p4 + 2u * j + 1u);
        float2 v0 = __half22float2(xs[qa.x & 0xFFFFFu]);
        float2 v1 = __half22float2(xs[qa.y & 0xFFFFFu]);
        float2 v2 = __half22float2(xs[qa.z & 0xFFFFFu]);
        float2 v3 = __half22float2(xs[qa.w & 0xFFFFFu]);
        float2 v4 = __half22float2(xs[qb.x & 0xFFFFFu]);
        float2 v5 = __half22float2(xs[qb.y & 0xFFFFFu]);
        float2 v6 = __half22float2(xs[qb.z & 0xFFFFFu]);
        float2 v7 = __half22float2(xs[qb.w & 0xFFFFFu]);
        atomicAdd(&acc[((qa.x >> 20) << 1) | par], pack2(v0.x, v0.y, SCALE1, BIAS1));
        atomicAdd(&acc[((qa.y >> 20) << 1) | par], pack2(v1.x, v1.y, SCALE1, BIAS1));
        atomicAdd(&acc[((qa.z >> 20) << 1) | par], pack2(v2.x, v2.y, SCALE1, BIAS1));
        atomicAdd(&acc[((qa.w >> 20) << 1) | par], pack2(v3.x, v3.y, SCALE1, BIAS1));
        atomicAdd(&acc[((qb.x >> 20) << 1) | par], pack2(v4.x, v4.y, SCALE1, BIAS1));
        atomicAdd(&acc[((qb.y >> 20) << 1) | par], pack2(v5.x, v5.y, SCALE1, BIAS1));
        atomicAdd(&acc[((qb.z >> 20) << 1) | par], pack2(v6.x, v6.y, SCALE1, BIAS1));
        atomicAdd(&acc[((qb.w >> 20) << 1) | par], pack2(v7.x, v7.y, SCALE1, BIAS1));
    }
    unsigned t = s + (nv8 << 3) + threadIdx.x;
    if (t < e) {
        unsigned p = perm[t];
        float2 v = __half22float2(xs[p & 0xFFFFFu]);
        atomicAdd(&acc[((p >> 20) << 1) | par], pack2(v.x, v.y, SCALE1, BIAS1));
    }
    __syncthreads();
    int d0 = b << W_SHIFT;
    float w10 = W1[0], w11 = W1[1], w12 = W1[2], w13 = W1[3];
    float w14 = W1[4], w15 = W1[5], w16 = W1[6], w17 = W1[7];
    float bb0 = b1[0], bb1 = b1[1], bb2 = b1[2], bb3 = b1[3];
    float u0 = W2[0], u1 = W2[1], u2 = W2[2], u3 = W2[3];
    float u4 = W2[4], u5 = W2[5], u6 = W2[6], u7 = W2[7];
    for (int l = threadIdx.x; l < W; l += AB) {
        int d = d0 + l;
        if (d < N) {
            float dv = dinv[d];
            unsigned cn = deg[d];
            unsigned long long a64 = acc[2 * l] + acc[2 * l + 1];
            unsigned lo = (unsigned)a64, hi = (unsigned)(a64 >> 32);
            float2 self = __half22float2(xs[d]);
            float Sx = (float)(int)(lo - cn * BIAS1) * INV1 + self.x;
            float Sy = (float)(int)(hi - cn * BIAS1) * INV1 + self.y;
            float a0 = fmaxf(fmaf(Sy, w14, Sx * w10) * dv + bb0, 0.0f);
            float a1 = fmaxf(fmaf(Sy, w15, Sx * w11) * dv + bb1, 0.0f);
            float a2 = fmaxf(fmaf(Sy, w16, Sx * w12) * dv + bb2, 0.0f);
            float a3 = fmaxf(fmaf(Sy, w17, Sx * w13) * dv + bb3, 0.0f);
            float hx = (a0 * u0 + a1 * u2 + a2 * u4 + a3 * u6) * dv;
            float hy = (a0 * u1 + a1 * u3 + a2 * u5 + a3 * u7) * dv;
            h2s[d] = __floats2half2_rn(hx, hy);
        }
    }
}

__global__ __launch_bounds__(AB) void k_acc2(const unsigned* __restrict__ perm,
                                             const unsigned* __restrict__ fill,
                                             const __half2* __restrict__ h2s,
                                             const float* __restrict__ dinv,
                                             const unsigned* __restrict__ deg,
                                             const float* __restrict__ b2,
                                             float2* __restrict__ out,
                                             int N, unsigned C) {
    __shared__ unsigned long long acc[2 * W];
    for (int i = threadIdx.x; i < 2 * W; i += AB) acc[i] = 0ull;
    __syncthreads();
    int b = blockIdx.x;
    unsigned par = threadIdx.x & 1u;
    unsigned s = (unsigned)b * C, e = fill[b];
    unsigned m = e - s, nv8 = m >> 3;
    const uv4* p4 = (const uv4*)(perm + s);
    for (unsigned j = threadIdx.x; j < nv8; j += AB) {
        uv4 qa = __builtin_nontemporal_load(p4 + 2u * j);
        uv4 qb = __builtin_nontemporal_load(p4 + 2u * j + 1u);
        float2 v0 = __half22float2(h2s[qa.x & 0xFFFFFu]);
        float2 v1 = __half22float2(h2s[qa.y & 0xFFFFFu]);
        float2 v2 = __half22float2(h2s[qa.z & 0xFFFFFu]);
        float2 v3 = __half22float2(h2s[qa.w & 0xFFFFFu]);
        float2 v4 = __half22float2(h2s[qb.x & 0xFFFFFu]);
        float2 v5 = __half22float2(h2s[qb.y & 0xFFFFFu]);
        float2 v6 = __half22float2(h2s[qb.z & 0xFFFFFu]);
        float2 v7 = __half22float2(h2s[qb.w & 0xFFFFFu]);
        atomicAdd(&acc[((qa.x >> 20) << 1) | par], pack2(v0.x, v0.y, SCALE2, BIAS2));
        atomicAdd(&acc[((qa.y >> 20) << 1) | par], pack2(v1.x, v1.y, SCALE2, BIAS2));
        atomicAdd(&acc[((qa.z >> 20) << 1) | par], pack2(v2.x, v2.y, SCALE2, BIAS2));
        atomicAdd(&acc[((qa.w >> 20) << 1) | par], pack2(v3.x, v3.y, SCALE2, BIAS2));
        atomicAdd(&acc[((qb.x >> 20) << 1) | par], pack2(v4.x, v4.y, SCALE2, BIAS2));
        atomicAdd(&acc[((qb.y >> 20) << 1) | par], pack2(v5.x, v5.y, SCALE2, BIAS2));
        atomicAdd(&acc[((qb.z >> 20) << 1) | par], pack2(v6.x, v6.y, SCALE2, BIAS2));
        atomicAdd(&acc[((qb.w >> 20) << 1) | par], pack2(v7.x, v7.y, SCALE2, BIAS2));
    }
    unsigned t = s + (nv8 << 3) + threadIdx.x;
    if (t < e) {
        unsigned p = perm[t];
        float2 v = __half22float2(h2s[p & 0xFFFFFu]);
        atomicAdd(&acc[((p >> 20) << 1) | par], pack2(v.x, v.y, SCALE2, BIAS2));
    }
    __syncthreads();
    int d0 = b << W_SHIFT;
    float bb0 = b2[0], bb1 = b2[1];
    for (int l = threadIdx.x; l < W; l += AB) {
        int d = d0 + l;
        if (d < N) {
            float dv = dinv[d];
            unsigned cn = deg[d];
            unsigned long long a64 = acc[2 * l] + acc[2 * l + 1];
            unsigned lo = (unsigned)a64, hi = (unsigned)(a64 >> 32);
            float2 v = __half22float2(h2s[d]);
            float Sx = (float)(int)(lo - cn * BIAS2) * INV2 + v.x;
            float Sy = (float)(int)(hi - cn * BIAS2) * INV2 + v.y;
            out[d] = make_float2(Sx * dv + bb0, Sy * dv + bb1);
        }
    }
}

// ---------------- fallback (R1-style, only if workspace too small) ----------

__global__ __launch_bounds__(256) void f_init_deg(unsigned* deg, int n) {
    int i = blockIdx.x * 256 + threadIdx.x;
    if (i < n) deg[i] = 1u;
}
__global__ __launch_bounds__(256) void f_count_deg(const int* dst, unsigned* deg, int E) {
    int e = blockIdx.x * 256 + threadIdx.x;
    if (e < E) atomicAdd(&deg[dst[e]], 1u);
}
__global__ __launch_bounds__(256) void f_node1(const float2* x, const float* W1,
                                               const unsigned* deg, float* dinv,
                                               float4* h1s, float4* agg1, int n) {
    int i = blockIdx.x * 256 + threadIdx.x;
    if (i >= n) return;
    float dv = 1.0f / sqrtf((float)deg[i]);
    dinv[i] = dv;
    float2 xv = x[i];
    float4 h;
    h.x = fmaf(xv.y, W1[4], xv.x * W1[0]) * dv;
    h.y = fmaf(xv.y, W1[5], xv.x * W1[1]) * dv;
    h.z = fmaf(xv.y, W1[6], xv.x * W1[2]) * dv;
    h.w = fmaf(xv.y, W1[7], xv.x * W1[3]) * dv;
    h1s[i] = h;
    agg1[i] = make_float4(h.x * dv, h.y * dv, h.z * dv, h.w * dv);
}
__global__ __launch_bounds__(256) void f_edge1(const int* src, const int* dst,
                                               const float* dinv, const float4* h1s,
                                               float* agg1, int E) {
    int e = blockIdx.x * 256 + threadIdx.x;
    if (e >= E) return;
    int s = src[e], d = dst[e];
    float w = dinv[d];
    float4 m = h1s[s];
    float* p = agg1 + 4ll * d;
    unsafeAtomicAdd(p + 0, m.x * w);
    unsafeAtomicAdd(p + 1, m.y * w);
    unsafeAtomicAdd(p + 2, m.z * w);
    unsafeAtomicAdd(p + 3, m.w * w);
}
__global__ __launch_bounds__(256) void f_node2(const float4* agg1, const float* b1,
                                               const float* W2, const float* b2,
                                               const float* dinv, float2* h2s,
                                               float2* out, int n) {
    int i = blockIdx.x * 256 + threadIdx.x;
    if (i >= n) return;
    float4 a = agg1[i];
    a.x = fmaxf(a.x + b1[0], 0.0f);
    a.y = fmaxf(a.y + b1[1], 0.0f);
    a.z = fmaxf(a.z + b1[2], 0.0f);
    a.w = fmaxf(a.w + b1[3], 0.0f);
    float dv = dinv[i];
    float2 h;
    h.x = (a.x * W2[0] + a.y * W2[2] + a.z * W2[4] + a.w * W2[6]) * dv;
    h.y = (a.x * W2[1] + a.y * W2[3] + a.z * W2[5] + a.w * W2[7]) * dv;
    h2s[i] = h;
    out[i] = make_float2(b2[0] + h.x * dv, b2[1] + h.y * dv);
}
__global__ __launch_bounds__(256) void f_edge2(const int* src, const int* dst,
                                               const float* dinv, const float2* h2s,
                                               float* out, int E) {
    int e = blockIdx.x * 256 + threadIdx.x;
    if (e >= E) return;
    int s = src[e], d = dst[e];
    float w = dinv[d];
    float2 m = h2s[s];
    float* p = out + 2ll * d;
    unsafeAtomicAdd(p + 0, m.x * w);
    unsafeAtomicAdd(p + 1, m.y * w);
}

extern "C" void kernel_launch(void* const* d_in, const int* in_sizes, int n_in,
                              void* d_out, int out_size, void* d_ws, size_t ws_size,
                              hipStream_t stream) {
    const float* x  = (const float*)d_in[0];
    const int* ei   = (const int*)d_in[1];
    const float* W1 = (const float*)d_in[2];
    const float* b1 = (const float*)d_in[3];
    const float* W2 = (const float*)d_in[4];
    const float* b2 = (const float*)d_in[5];
    float* out = (float*)d_out;

    const int N = in_sizes[0] / 2;
    const int E = in_sizes[1] / 2;
    const int* src = ei;
    const int* dst = ei + E;
    const int NB = (N + W - 1) >> W_SHIFT;

    char* ws = (char*)d_ws;
    const int gN = (N + 255) / 256;
    const int gE = (E + 255) / 256;

    // slab capacity: mean fill E/NB (~32.7K, sigma~181); margin 4096 (>20σ)
    size_t fixed = 32768 + (size_t)16 * N;   // fill | dinv | deg | xs | h2s
    long avail = (long)ws_size - (long)fixed;
    long Cmax = (avail > 0) ? avail / (4L * NB) : 0;
    long Cmin = (long)(E / (NB > 0 ? NB : 1)) + 4096;
    long Cw = (Cmax > Cmin + 8192) ? (Cmin + 8192) : Cmax;
    unsigned C = (unsigned)(Cw & ~7L);       // multiple of 8 for uint4x2 loads
    bool fast = ((long)C >= Cmin) && (NB <= MAXB) && (N <= (1 << 20));

    if (fast) {
        unsigned* fill = (unsigned*)(ws);                          // NB entries
        float*    dinv = (float*)(ws + 32768);
        unsigned* deg  = (unsigned*)(ws + 32768 + (size_t)4 * N);
        __half2*  xs   = (__half2*)(ws + 32768 + (size_t)8 * N);
        __half2*  h2s  = (__half2*)(ws + 32768 + (size_t)12 * N);
        unsigned* perm = (unsigned*)(ws + fixed);

        k_zero_fill<<<(NB + 255) / 256, 256, 0, stream>>>(fill, NB, C);
        k_reorder<<<(E + CHUNK - 1) / CHUNK, RB, 0, stream>>>(src, dst, fill, perm, E);
        k_dinv<<<NB, AB, 0, stream>>>(perm, fill, (const float2*)x, dinv, deg, xs, N, C);
        k_acc1<<<NB, AB, 0, stream>>>(perm, fill, xs, dinv, deg, W1, b1, W2, h2s, N, C);
        k_acc2<<<NB, AB, 0, stream>>>(perm, fill, h2s, dinv, deg, b2, (float2*)out, N, C);
    } else {
        unsigned* deg = (unsigned*)(ws);
        float* dinv   = (float*)(ws + (size_t)4 * N);
        float* h1s    = (float*)(ws + (size_t)8 * N);
        float* agg1   = (float*)(ws + (size_t)24 * N);
        float* h2s    = h1s;

        f_init_deg<<<gN, 256, 0, stream>>>(deg, N);
        f_count_deg<<<gE, 256, 0, stream>>>(dst, deg, E);
        f_node1<<<gN, 256, 0, stream>>>((const float2*)x, W1, deg, dinv,
                                        (float4*)h1s, (float4*)agg1, N);
        f_edge1<<<gE, 256, 0, stream>>>(src, dst, dinv, (const float4*)h1s, agg1, E);
        f_node2<<<gN, 256, 0, stream>>>((const float4*)agg1, b1, W2, b2, dinv,
                                        (float2*)h2s, (float2*)out, N);
        f_edge2<<<gE, 256, 0, stream>>>(src, dst, dinv, (const float2*)h2s, out, E);
    }
}